// Round 1
// 332.359 us; speedup vs baseline: 1.4903x; 1.4903x over previous
//
#include <hip/hip_runtime.h>
#include <math.h>

#define NTOK 4096
#define DDIM 1024
#define HDIM 4096
#define NEXP 8
#define BK 64

typedef float f32x4 __attribute__((ext_vector_type(4)));
typedef __bf16 bf16x8 __attribute__((ext_vector_type(8)));
typedef const __attribute__((address_space(1))) void gas_t;
typedef __attribute__((address_space(3))) void las_t;

__device__ __forceinline__ unsigned short f2bf(float f) {
    union { float f; unsigned u; } v; v.f = f;
    unsigned u = v.u;
    return (unsigned short)((u + 0x7fffu + ((u >> 16) & 1u)) >> 16);
}

__device__ __forceinline__ float gelu_f(float v) {
    return 0.5f * v * (1.0f + erff(v * 0.70710678118654752f));
}

// ---------------- gating: one wave per token ----------------
__global__ void k_gate(const float* __restrict__ x, const float* __restrict__ gw,
                       const float* __restrict__ gb, int* __restrict__ sel,
                       int* __restrict__ counts) {
    const int wid = threadIdx.x >> 6, lane = threadIdx.x & 63;
    const int tok = blockIdx.x * 4 + wid;
    const float* xr = x + (long)tok * DDIM;
    float s[NEXP];
#pragma unroll
    for (int e = 0; e < NEXP; ++e) s[e] = 0.f;
    for (int it = 0; it < DDIM / 64; ++it) {
        const int kk = it * 64 + lane;
        const float xv = xr[kk];
        const float4* g4 = (const float4*)(gw + (long)kk * NEXP);
        const float4 g0 = g4[0], g1 = g4[1];
        s[0] += xv * g0.x; s[1] += xv * g0.y; s[2] += xv * g0.z; s[3] += xv * g0.w;
        s[4] += xv * g1.x; s[5] += xv * g1.y; s[6] += xv * g1.z; s[7] += xv * g1.w;
    }
#pragma unroll
    for (int e = 0; e < NEXP; ++e)
        for (int off = 32; off > 0; off >>= 1)
            s[e] += __shfl_down(s[e], off);
    if (lane == 0) {
        float best = s[0] + gb[0]; int bi = 0;
#pragma unroll
        for (int e = 1; e < NEXP; ++e) {
            const float v = s[e] + gb[e];
            if (v > best) { best = v; bi = e; }   // strict > keeps lowest index on ties (np.argmax)
        }
        sel[tok] = bi;
        atomicAdd(&counts[bi], 1);
    }
}

// ---------------- scan (tiny) ----------------
__global__ void k_scan(const int* __restrict__ counts, int* __restrict__ offs,
                       int* __restrict__ cursors, float* __restrict__ laux) {
    if (threadIdx.x == 0 && blockIdx.x == 0) {
        int o = 0;
        for (int e = 0; e < NEXP; ++e) { offs[e] = o; cursors[e] = o; o += counts[e]; }
        offs[NEXP] = o;
        laux[0] = 0.f;
    }
}

// ---------------- fill token lists ----------------
__global__ void k_fill(const int* __restrict__ sel, int* __restrict__ cursors,
                       int* __restrict__ list) {
    const int t = blockIdx.x * blockDim.x + threadIdx.x;
    if (t < NTOK) {
        const int e = sel[t];
        const int slot = atomicAdd(&cursors[e], 1);
        list[slot] = t;
    }
}

// ---------------- x -> bf16 (one shot) ----------------
__global__ __launch_bounds__(256) void k_cvt_x(const float* __restrict__ x,
                                               unsigned short* __restrict__ xb) {
    const long i = ((long)blockIdx.x * 256 + threadIdx.x) * 8;
    const float4 a = *(const float4*)(x + i);
    const float4 b = *(const float4*)(x + i + 4);
    *(ushort4*)(xb + i)     = make_ushort4(f2bf(a.x), f2bf(a.y), f2bf(a.z), f2bf(a.w));
    *(ushort4*)(xb + i + 4) = make_ushort4(f2bf(b.x), f2bf(b.y), f2bf(b.z), f2bf(b.w));
}

// ---------------- W [e][K][NC] f32 -> Wt [e][NC][K] bf16 (transpose-convert) ----------------
template<int K, int NC>
__global__ __launch_bounds__(256) void k_cvt_w(const float* __restrict__ W,
                                               unsigned short* __restrict__ Wt) {
    __shared__ unsigned short T[64 * 68];   // [n][k], stride 68 breaks bank conflicts
    const int ktiles = K / 64;
    const int e  = blockIdx.y / ktiles;
    const int k0 = (blockIdx.y % ktiles) * 64;
    const int n0 = blockIdx.x * 64;
    const float* src = W + (long)e * K * NC + (long)k0 * NC + n0;
    const int tid = threadIdx.x;
#pragma unroll
    for (int i = 0; i < 4; ++i) {
        const int idx = tid + i * 256;          // 0..1023 over 64k x 16 float4
        const int k = idx >> 4, c4 = (idx & 15) * 4;
        const float4 v = *(const float4*)(src + (long)k * NC + c4);
        T[(c4 + 0) * 68 + k] = f2bf(v.x);
        T[(c4 + 1) * 68 + k] = f2bf(v.y);
        T[(c4 + 2) * 68 + k] = f2bf(v.z);
        T[(c4 + 3) * 68 + k] = f2bf(v.w);
    }
    __syncthreads();
    unsigned short* dst = Wt + (long)e * NC * K + (long)n0 * K + k0;
#pragma unroll
    for (int i = 0; i < 2; ++i) {
        const int idx = tid + i * 256;          // 0..511 over 64n x 8 chunks
        const int n = idx >> 3, c8 = (idx & 7) * 8;
        *(ushort4*)(dst + (long)n * K + c8)     = *(const ushort4*)&T[n * 68 + c8];
        *(ushort4*)(dst + (long)n * K + c8 + 4) = *(const ushort4*)&T[n * 68 + c8 + 4];
    }
}

// ---------------- grouped GEMM (m97 structure: global_load_lds + XOR swizzle) ----------------
// MODE 0: H = gelu(gather(xb) @ W1t^T + b1)  -> Hws (bf16, by slot)
// MODE 1: out[tok] = Hws @ W2t^T + b2        -> out (fp32, scatter)
// A rows: Ain[row][K] bf16; B rows: Wt[e][n][K] bf16. Swizzle via per-lane global source.
template<int MODE, int BM_, int BN_>
__global__ __launch_bounds__(256) void k_gemm(
        const unsigned short* __restrict__ Ain,
        const unsigned short* __restrict__ Wt,
        const float* __restrict__ bias,
        unsigned short* __restrict__ Hout, float* __restrict__ Yout,
        const int* __restrict__ counts, const int* __restrict__ offs,
        const int* __restrict__ list) {
    static_assert(BM_ % 32 == 0 && BN_ % 32 == 0, "tile");
    constexpr int K  = (MODE == 0) ? DDIM : HDIM;
    constexpr int NC = (MODE == 0) ? HDIM : DDIM;
    constexpr int MT = NTOK / BM_;
    constexpr int FM = BM_ / 32;                 // 16-row frags per wave (2x2 wave grid)
    constexpr int FN = BN_ / 32;
    const int e   = blockIdx.y / MT;
    const int mt  = blockIdx.y % MT;
    const int cnt = counts[e];
    const int m0  = mt * BM_;
    if (m0 >= cnt) return;
    const int base = offs[e];
    const int n0   = blockIdx.x * BN_;

    __shared__ __align__(16) unsigned short As[BM_ * 64];   // [m][64k], 128B rows, swizzled
    __shared__ __align__(16) unsigned short Bt[BN_ * 64];   // [n][64k], 128B rows, swizzled

    const int tid  = threadIdx.x;
    const int lane = tid & 63, wid = tid >> 6;
    const int lr = lane >> 3, lc = lane & 7;
    const int sb = (lc * 16) ^ (lr << 4);        // pre-swizzled source byte offset

    // per-lane global source pointers (row&7 == lr by construction, so sb is loop-invariant)
    const unsigned short* pA[BM_ / 32];
#pragma unroll
    for (int i = 0; i < BM_ / 32; ++i) {
        const int r = wid * (BM_ / 4) + i * 8 + lr;
        int rr = m0 + r; if (rr >= cnt) rr = cnt - 1;
        const long row = (MODE == 0) ? (long)list[base + rr] : (long)(base + rr);
        pA[i] = (const unsigned short*)((const char*)(Ain + row * K) + sb);
    }
    const unsigned short* We = Wt + (long)e * NC * K;
    const unsigned short* pB[BN_ / 32];
#pragma unroll
    for (int i = 0; i < BN_ / 32; ++i) {
        const int r = wid * (BN_ / 4) + i * 8 + lr;
        pB[i] = (const unsigned short*)((const char*)(We + (long)(n0 + r) * K) + sb);
    }

    const int wm = (wid >> 1) * (BM_ / 2);
    const int wn = (wid & 1) * (BN_ / 2);
    const int hk = 16 * (lane >> 4);

    const f32x4 zero4 = {0.f, 0.f, 0.f, 0.f};
    f32x4 acc[FM][FN];
#pragma unroll
    for (int i = 0; i < FM; ++i)
#pragma unroll
        for (int j = 0; j < FN; ++j) acc[i][j] = zero4;

    for (int k0 = 0; k0 < K; k0 += BK) {
        __syncthreads();   // prior-iter readers done (implicit vmcnt/lgkmcnt drain)
#pragma unroll
        for (int i = 0; i < BM_ / 32; ++i)
            __builtin_amdgcn_global_load_lds((gas_t*)(pA[i] + k0),
                (las_t*)(As + wid * (BM_ / 4) * 64 + i * 512), 16, 0, 0);
#pragma unroll
        for (int i = 0; i < BN_ / 32; ++i)
            __builtin_amdgcn_global_load_lds((gas_t*)(pB[i] + k0),
                (las_t*)(Bt + wid * (BN_ / 4) * 64 + i * 512), 16, 0, 0);
        __syncthreads();   // staging complete
#pragma unroll
        for (int kk = 0; kk < BK; kk += 32) {
            bf16x8 a[FM], b[FN];
#pragma unroll
            for (int mf = 0; mf < FM; ++mf) {
                const int r  = wm + mf * 16 + (lane & 15);
                const int kb = (2 * kk + hk) ^ ((r & 7) << 4);
                a[mf] = *(const bf16x8*)((const char*)As + r * 128 + kb);
            }
#pragma unroll
            for (int nf = 0; nf < FN; ++nf) {
                const int c  = wn + nf * 16 + (lane & 15);
                const int kb = (2 * kk + hk) ^ ((c & 7) << 4);
                b[nf] = *(const bf16x8*)((const char*)Bt + c * 128 + kb);
            }
#pragma unroll
            for (int mf = 0; mf < FM; ++mf)
#pragma unroll
                for (int nf = 0; nf < FN; ++nf)
                    acc[mf][nf] = __builtin_amdgcn_mfma_f32_16x16x32_bf16(
                        a[mf], b[nf], acc[mf][nf], 0, 0, 0);
        }
    }
    // ---- epilogue ----
#pragma unroll
    for (int nf = 0; nf < FN; ++nf) {
        const int col = n0 + wn + nf * 16 + (lane & 15);
        const float bv = bias[(long)e * NC + col];
#pragma unroll
        for (int mf = 0; mf < FM; ++mf) {
            const int rb = m0 + wm + mf * 16 + (lane >> 4) * 4;
#pragma unroll
            for (int ri = 0; ri < 4; ++ri) {
                const int row = rb + ri;
                if (row < cnt) {
                    const float v = acc[mf][nf][ri] + bv;
                    if constexpr (MODE == 0)
                        Hout[(long)(base + row) * HDIM + col] = f2bf(gelu_f(v));
                    else
                        Yout[(long)list[base + row] * DDIM + col] = v;
                }
            }
        }
    }
}

extern "C" void kernel_launch(void* const* d_in, const int* in_sizes, int n_in,
                              void* d_out, int out_size, void* d_ws, size_t ws_size,
                              hipStream_t stream) {
    const float* x      = (const float*)d_in[0];
    const float* gate_w = (const float*)d_in[1];
    const float* gate_b = (const float*)d_in[2];
    const float* w1     = (const float*)d_in[3];
    const float* b1     = (const float*)d_in[4];
    const float* w2     = (const float*)d_in[5];
    const float* b2     = (const float*)d_in[6];
    float* out = (float*)d_out;

    // workspace layout
    char* ws = (char*)d_ws;
    int* counts  = (int*)(ws);                 // 8
    int* cursors = (int*)(ws + 128);           // 8
    int* offs    = (int*)(ws + 256);           // 9
    int* sel     = (int*)(ws + 1024);          // 4096
    int* list    = (int*)(ws + 1024 + 16384);  // 4096
    unsigned short* xb  = (unsigned short*)(ws + 65536);                    // 8 MB
    unsigned short* Hws = (unsigned short*)(ws + 65536 + 8388608);          // 33.5 MB
    unsigned short* Wtb = (unsigned short*)(ws + 65536 + 8388608 + 33554432); // 67 MB (reused W1t then W2t)
    const size_t WS_NEEDED = 65536 + 8388608 + 33554432 + 67108864;
    if (ws_size < WS_NEEDED) return;  // deterministic fail, no corruption

    hipMemsetAsync(ws, 0, 1024, stream);
    k_gate<<<NTOK / 4, 256, 0, stream>>>(x, gate_w, gate_b, sel, counts);
    k_scan<<<1, 64, 0, stream>>>(counts, offs, cursors, out + (long)NTOK * DDIM);
    k_fill<<<(NTOK + 255) / 256, 256, 0, stream>>>(sel, cursors, list);
    k_cvt_x<<<(NTOK * DDIM) / (256 * 8), 256, 0, stream>>>(x, xb);

    // W1t = transpose-convert(w1), then FFN up+gelu
    k_cvt_w<DDIM, HDIM><<<dim3(HDIM / 64, NEXP * (DDIM / 64)), 256, 0, stream>>>(w1, Wtb);
    k_gemm<0, 128, 128><<<dim3(HDIM / 128, NEXP * (NTOK / 128)), 256, 0, stream>>>(
        xb, Wtb, b1, Hws, nullptr, counts, offs, list);

    // W2t = transpose-convert(w2) into the SAME buffer (w1 no longer needed), then FFN down
    k_cvt_w<HDIM, DDIM><<<dim3(DDIM / 64, NEXP * (HDIM / 64)), 256, 0, stream>>>(w2, Wtb);
    k_gemm<1, 64, 128><<<dim3(DDIM / 128, NEXP * (NTOK / 64)), 256, 0, stream>>>(
        Hws, Wtb, b2, nullptr, out, counts, offs, list);
}